// Round 13
// baseline (258.482 us; speedup 1.0000x reference)
//
#include <hip/hip_runtime.h>
#include <hip/hip_bf16.h>

#define NN 50000
#define EE 1600000
#define SENT EE              // sentinel edge index: w=0, next=SENT (self-sticking)
#define PROJ_BLOCKS 1563     // ceil(NN/32) 32-row MFMA tiles

using short8 = __attribute__((ext_vector_type(8))) short;   // 8 bf16 (4 VGPRs)
using float4v = __attribute__((ext_vector_type(4))) float;  // MFMA accumulator

__device__ __forceinline__ float bflo(unsigned u) { return __uint_as_float(u << 16); }
__device__ __forceinline__ float bfhi(unsigned u) { return __uint_as_float(u & 0xffff0000u); }
__device__ __forceinline__ unsigned short f2bf(float v) {
  return __bfloat16_as_ushort(__float2bfloat16(v));
}

// ---------------- K0: a_src/a_dst via collapsed matvec + head8/sentinel init ----------
// a_src[n,h] = sum_k elu(x[n,k]) * (W @ att_src^T)[k,h]. One wave per node.
__global__ __launch_bounds__(256) void k_pre(
    const float* __restrict__ x, const float* __restrict__ W,
    const float* __restrict__ att_src, const float* __restrict__ att_dst,
    float2* __restrict__ a_src2, float2* __restrict__ a_dst2,
    int* __restrict__ head8, int4* __restrict__ edge4, int nblocks) {
  __shared__ float wa_s[128][2], wa_d[128][2];
  int tid = threadIdx.x;
  {
    int k = tid >> 1, hh = tid & 1;
    const float* wrow = W + k * 64 + hh * 32;
    const float* as = att_src + hh * 32;
    const float* ad = att_dst + hh * 32;
    float ss = 0.f, dd = 0.f;
#pragma unroll 8
    for (int c = 0; c < 32; ++c) { float wv = wrow[c]; ss += wv * as[c]; dd += wv * ad[c]; }
    wa_s[k][hh] = ss; wa_d[k][hh] = dd;
  }
  int gsize = nblocks * 256;
  for (int i = blockIdx.x * 256 + tid; i < NN * 8; i += gsize) head8[i] = SENT;
  if (blockIdx.x == 0 && tid == 0) edge4[SENT] = make_int4(0, SENT, 0, 0);
  __syncthreads();
  int w = tid >> 6, lane = tid & 63;
  int nwaves = nblocks * 4;
  for (int n = blockIdx.x * 4 + w; n < NN; n += nwaves) {
    float x0 = x[n * 128 + lane], x1 = x[n * 128 + 64 + lane];
    x0 = x0 > 0.f ? x0 : __expf(x0) - 1.f;
    x1 = x1 > 0.f ? x1 : __expf(x1) - 1.f;
    float s0 = x0 * wa_s[lane][0] + x1 * wa_s[lane + 64][0];
    float s1 = x0 * wa_s[lane][1] + x1 * wa_s[lane + 64][1];
    float d0 = x0 * wa_d[lane][0] + x1 * wa_d[lane + 64][0];
    float d1 = x0 * wa_d[lane][1] + x1 * wa_d[lane + 64][1];
#pragma unroll
    for (int o = 32; o > 0; o >>= 1) {
      s0 += __shfl_xor(s0, o); s1 += __shfl_xor(s1, o);
      d0 += __shfl_xor(d0, o); d1 += __shfl_xor(d1, o);
    }
    if (lane == 0) { a_src2[n] = make_float2(s0, s1); a_dst2[n] = make_float2(d0, d1); }
  }
}

// ---------------- K1: FUSED  [blocks < PROJ_BLOCKS]: h = elu(x)@W via bf16 MFMA
//                          [blocks >= PROJ_BLOCKS]: list build + edge weights ----------
// Proj and build are independent (both depend only on k_pre/inputs); fusing them
// co-schedules LDS/MFMA-bound proj waves with atomic/latency-bound build waves.
// LDS trimmed to 26.2 KB (32-row tiles) so build blocks keep 6 blocks/CU.
__global__ __launch_bounds__(256) void k_mid(
    const float* __restrict__ x, const float* __restrict__ W,
    const int* __restrict__ src, const int* __restrict__ dst,
    const float2* __restrict__ a_src2, const float2* __restrict__ a_dst2,
    int* __restrict__ head8, int4* __restrict__ edge4, unsigned* __restrict__ h2u) {
  int bid = blockIdx.x;
  int tid = threadIdx.x;
  if (bid >= PROJ_BLOCKS) {
    // ---- build part: one lane per edge; single random atomicExch (L2-hot 1.6 MB);
    //      coalesced 16 B record (src, next, w0, w1) ----
    int e = (bid - PROJ_BLOCKS) * 256 + tid;
    int s = src[e], d = dst[e];
    float2 as = a_src2[s], ad = a_dst2[d];
    float l0 = as.x + ad.x; l0 = fmaxf(l0, 0.2f * l0);
    float l1 = as.y + ad.y; l1 = fmaxf(l1, 0.2f * l1);
    int old = atomicExch(&head8[d * 8 + (e & 7)], e);
    edge4[e] = make_int4(s, old, __float_as_int(__expf(l0)), __float_as_int(__expf(l1)));
    return;
  }
  // ---- proj part: 32 rows/block; wave w -> row-tile w>>1, col-tiles (w&1)*2+{0,1} ----
  __shared__ unsigned short Wt[64 * 136];   // [n][k] bf16 (W^T), padded, 17.4 KB
  __shared__ unsigned short xs[32 * 136];   // [r][k] bf16 (ELU applied), 8.7 KB
  int row0 = bid * 32;
  for (int i = tid; i < 8192; i += 256) {          // stage W^T
    int k = i >> 6, n = i & 63;
    Wt[n * 136 + k] = f2bf(W[i]);
  }
  for (int i = tid; i < 2048; i += 256) {          // stage x rows (ELU, bf16, packed)
    int r = i >> 6, k2 = (i & 63) * 2;
    int row = row0 + r;
    float v0 = 0.f, v1 = 0.f;
    if (row < NN) { float2 xv = *(const float2*)&x[row * 128 + k2]; v0 = xv.x; v1 = xv.y; }
    v0 = v0 > 0.f ? v0 : __expf(v0) - 1.f;
    v1 = v1 > 0.f ? v1 : __expf(v1) - 1.f;
    *(unsigned*)&xs[r * 136 + k2] = (unsigned)f2bf(v0) | ((unsigned)f2bf(v1) << 16);
  }
  __syncthreads();
  int w = tid >> 6, lane = tid & 63;
  int t = w >> 1, ch = w & 1;               // row-tile, column-half
  int m = lane & 15, quad = lane >> 4;
  float4v acc[2] = {{0, 0, 0, 0}, {0, 0, 0, 0}};
#pragma unroll
  for (int ks = 0; ks < 4; ++ks) {
    int koff = quad * 8 + ks * 32;
    short8 af = *(const short8*)&xs[(t * 16 + m) * 136 + koff];
#pragma unroll
    for (int j = 0; j < 2; ++j) {
      int nt = ch * 2 + j;
      short8 bf = *(const short8*)&Wt[(nt * 16 + m) * 136 + koff];
      acc[j] = __builtin_amdgcn_mfma_f32_16x16x32_bf16(af, bf, acc[j], 0, 0, 0);
    }
  }
#pragma unroll
  for (int j = 0; j < 2; ++j) {
    int nt = ch * 2 + j;
#pragma unroll
    for (int reg = 0; reg < 4; ++reg) {
      float v = acc[j][reg];
      float vhi = __shfl_xor(v, 1);          // partner column (m^1)
      int row = row0 + t * 16 + quad * 4 + reg;
      if (!(m & 1) && row < NN) {
        h2u[row * 32 + nt * 8 + (m >> 1)] =
            (unsigned)f2bf(v) | ((unsigned)f2bf(vhi) << 16);
      }
    }
  }
}

// ---------------- K2: weighted aggregate, sentinel chase ----------------
// one wave per dst node; half-wave chases 4 of 8 chains. Dead chains stick on the
// sentinel record (w=0, next=SENT, L2-hot) -> no max/cndmask bookkeeping per iter.
__global__ __launch_bounds__(256) void k_agg(
    const unsigned* __restrict__ h2u, const float2* __restrict__ a_src2,
    const float2* __restrict__ a_dst2, const int4* __restrict__ head8v,
    const int4* __restrict__ edge4, const float* __restrict__ bias,
    float* __restrict__ out) {
  int n = blockIdx.x * 4 + (threadIdx.x >> 6);
  int lane = threadIdx.x & 63;
  int c2 = lane & 31;          // column pair: cols 2*c2, 2*c2+1
  int half = lane >> 5;
  int hh = c2 >> 4;

  float denom = 0.f, acc0 = 0.f, acc1 = 0.f;
  if (half == 0) {             // self loop (PyG add_self_loops), counted once
    float2 as = a_src2[n], ad = a_dst2[n];
    float l0 = (hh ? as.y + ad.y : as.x + ad.x);
    l0 = fmaxf(l0, 0.2f * l0);
    float es = __expf(l0);
    unsigned hv = h2u[n * 32 + c2];
    denom = es; acc0 = es * bflo(hv); acc1 = es * bfhi(hv);
  }

  int4 hd = head8v[n * 2 + half];    // 4 chain heads in one 16 B load
  int e0 = hd.x, e1 = hd.y, e2 = hd.z, e3 = hd.w;
  while (__any(((e0 != SENT) | (e1 != SENT) | (e2 != SENT) | (e3 != SENT)) != 0)) {
    int4 p0 = edge4[e0];
    int4 p1 = edge4[e1];
    int4 p2 = edge4[e2];
    int4 p3 = edge4[e3];
    unsigned h0 = h2u[p0.x * 32 + c2], h1 = h2u[p1.x * 32 + c2];
    unsigned h2 = h2u[p2.x * 32 + c2], h3 = h2u[p3.x * 32 + c2];
    float x0 = __int_as_float(hh ? p0.w : p0.z);   // sentinel contributes 0 naturally
    float x1 = __int_as_float(hh ? p1.w : p1.z);
    float x2 = __int_as_float(hh ? p2.w : p2.z);
    float x3 = __int_as_float(hh ? p3.w : p3.z);
    denom += (x0 + x1) + (x2 + x3);
    acc0 += x0 * bflo(h0) + x1 * bflo(h1) + x2 * bflo(h2) + x3 * bflo(h3);
    acc1 += x0 * bfhi(h0) + x1 * bfhi(h1) + x2 * bfhi(h2) + x3 * bfhi(h3);
    e0 = p0.y; e1 = p1.y; e2 = p2.y; e3 = p3.y;    // sentinel self-loops
  }
  denom += __shfl_xor(denom, 32);
  acc0  += __shfl_xor(acc0, 32);
  acc1  += __shfl_xor(acc1, 32);
  if (half == 0) {
    float inv = 1.f / (denom + 1e-16f);
    float2 b = ((const float2*)bias)[c2];
    ((float2*)out)[n * 32 + c2] = make_float2(acc0 * inv + b.x, acc1 * inv + b.y);
  }
}

extern "C" void kernel_launch(void* const* d_in, const int* in_sizes, int n_in,
                              void* d_out, int out_size, void* d_ws, size_t ws_size,
                              hipStream_t stream) {
  const float* x       = (const float*)d_in[0];
  const float* W       = (const float*)d_in[1];
  const float* att_src = (const float*)d_in[2];
  const float* att_dst = (const float*)d_in[3];
  const float* bias    = (const float*)d_in[4];
  const int* edge_index = (const int*)d_in[5];
  const int* esrc = edge_index;        // edge_index[0, :]
  const int* edst = edge_index + EE;   // edge_index[1, :]

  // Workspace layout:
  char* base = (char*)d_ws;
  unsigned* h2u  = (unsigned*)base;                      // [0     .. 6.4M)   h bf16x2
  float2* a_src2 = (float2*)(base + 6400000);            // [6.4M  .. 6.8M)  50K float2
  float2* a_dst2 = (float2*)(base + 6800000);            // [6.8M  .. 7.2M)  50K float2
  int*    head8  = (int*)(base + 7200000);               // [7.2M  .. 8.8M)  400K i32
  int4*   edge4  = (int4*)(base + 8800000);              // [8.8M  .. ~34.4M) EE+1 int4

  const int PRE_BLOCKS = 1024;
  k_pre<<<PRE_BLOCKS, 256, 0, stream>>>(x, W, att_src, att_dst, a_src2, a_dst2,
                                        head8, edge4, PRE_BLOCKS);
  k_mid<<<PROJ_BLOCKS + EE / 256, 256, 0, stream>>>(x, W, esrc, edst, a_src2,
                                                    a_dst2, head8, edge4, h2u);
  k_agg<<<NN / 4, 256, 0, stream>>>(h2u, a_src2, a_dst2, (const int4*)head8,
                                    edge4, bias, (float*)d_out);
}

// Round 14
// 239.027 us; speedup vs baseline: 1.0814x; 1.0814x over previous
//
#include <hip/hip_runtime.h>
#include <hip/hip_bf16.h>

#define NN 50000
#define EE 1600000
#define PROJ_BLOCKS 1563     // ceil(NN/32) 32-row MFMA tiles

using short8 = __attribute__((ext_vector_type(8))) short;   // 8 bf16 (4 VGPRs)
using float4v = __attribute__((ext_vector_type(4))) float;  // MFMA accumulator

__device__ __forceinline__ float bflo(unsigned u) { return __uint_as_float(u << 16); }
__device__ __forceinline__ float bfhi(unsigned u) { return __uint_as_float(u & 0xffff0000u); }
__device__ __forceinline__ unsigned short f2bf(float v) {
  return __bfloat16_as_ushort(__float2bfloat16(v));
}

// ---------------- K0: a_src/a_dst via collapsed matvec + head8 init ----------------
// a_src[n,h] = sum_k elu(x[n,k]) * (W @ att_src^T)[k,h]. One wave per node.
__global__ __launch_bounds__(256) void k_pre(
    const float* __restrict__ x, const float* __restrict__ W,
    const float* __restrict__ att_src, const float* __restrict__ att_dst,
    float2* __restrict__ a_src2, float2* __restrict__ a_dst2,
    int* __restrict__ head8, int nblocks) {
  __shared__ float wa_s[128][2], wa_d[128][2];
  int tid = threadIdx.x;
  {
    int k = tid >> 1, hh = tid & 1;
    const float* wrow = W + k * 64 + hh * 32;
    const float* as = att_src + hh * 32;
    const float* ad = att_dst + hh * 32;
    float ss = 0.f, dd = 0.f;
#pragma unroll 8
    for (int c = 0; c < 32; ++c) { float wv = wrow[c]; ss += wv * as[c]; dd += wv * ad[c]; }
    wa_s[k][hh] = ss; wa_d[k][hh] = dd;
  }
  int gsize = nblocks * 256;
  for (int i = blockIdx.x * 256 + tid; i < NN * 8; i += gsize) head8[i] = -1;
  __syncthreads();
  int w = tid >> 6, lane = tid & 63;
  int nwaves = nblocks * 4;
  for (int n = blockIdx.x * 4 + w; n < NN; n += nwaves) {
    float x0 = x[n * 128 + lane], x1 = x[n * 128 + 64 + lane];
    x0 = x0 > 0.f ? x0 : __expf(x0) - 1.f;
    x1 = x1 > 0.f ? x1 : __expf(x1) - 1.f;
    float s0 = x0 * wa_s[lane][0] + x1 * wa_s[lane + 64][0];
    float s1 = x0 * wa_s[lane][1] + x1 * wa_s[lane + 64][1];
    float d0 = x0 * wa_d[lane][0] + x1 * wa_d[lane + 64][0];
    float d1 = x0 * wa_d[lane][1] + x1 * wa_d[lane + 64][1];
#pragma unroll
    for (int o = 32; o > 0; o >>= 1) {
      s0 += __shfl_xor(s0, o); s1 += __shfl_xor(s1, o);
      d0 += __shfl_xor(d0, o); d1 += __shfl_xor(d1, o);
    }
    if (lane == 0) { a_src2[n] = make_float2(s0, s1); a_dst2[n] = make_float2(d0, d1); }
  }
}

// ---------------- K1: FUSED  [blocks < PROJ_BLOCKS]: h = elu(x)@W via bf16 MFMA
//                          [blocks >= PROJ_BLOCKS]: list build + edge weights ----------
// Proj and build are independent (both depend only on k_pre/inputs); fusing them
// co-schedules LDS/MFMA-bound proj waves with atomic/latency-bound build waves.
// (Measured R13: fusion cut the residual 175.8 -> 164.4 us.)
__global__ __launch_bounds__(256) void k_mid(
    const float* __restrict__ x, const float* __restrict__ W,
    const int* __restrict__ src, const int* __restrict__ dst,
    const float2* __restrict__ a_src2, const float2* __restrict__ a_dst2,
    int* __restrict__ head8, int4* __restrict__ edge4, unsigned* __restrict__ h2u) {
  int bid = blockIdx.x;
  int tid = threadIdx.x;
  if (bid >= PROJ_BLOCKS) {
    // ---- build part: one lane per edge; single random atomicExch (L2-hot 1.6 MB);
    //      coalesced 16 B record (src, next, w0, w1) ----
    int e = (bid - PROJ_BLOCKS) * 256 + tid;
    int s = src[e], d = dst[e];
    float2 as = a_src2[s], ad = a_dst2[d];
    float l0 = as.x + ad.x; l0 = fmaxf(l0, 0.2f * l0);
    float l1 = as.y + ad.y; l1 = fmaxf(l1, 0.2f * l1);
    int old = atomicExch(&head8[d * 8 + (e & 7)], e);
    edge4[e] = make_int4(s, old, __float_as_int(__expf(l0)), __float_as_int(__expf(l1)));
    return;
  }
  // ---- proj part: 32 rows/block; wave w -> row-tile w>>1, col-tiles (w&1)*2+{0,1} ----
  __shared__ unsigned short Wt[64 * 136];   // [n][k] bf16 (W^T), padded, 17.4 KB
  __shared__ unsigned short xs[32 * 136];   // [r][k] bf16 (ELU applied), 8.7 KB
  int row0 = bid * 32;
  for (int i = tid; i < 8192; i += 256) {          // stage W^T
    int k = i >> 6, n = i & 63;
    Wt[n * 136 + k] = f2bf(W[i]);
  }
  for (int i = tid; i < 2048; i += 256) {          // stage x rows (ELU, bf16, packed)
    int r = i >> 6, k2 = (i & 63) * 2;
    int row = row0 + r;
    float v0 = 0.f, v1 = 0.f;
    if (row < NN) { float2 xv = *(const float2*)&x[row * 128 + k2]; v0 = xv.x; v1 = xv.y; }
    v0 = v0 > 0.f ? v0 : __expf(v0) - 1.f;
    v1 = v1 > 0.f ? v1 : __expf(v1) - 1.f;
    *(unsigned*)&xs[r * 136 + k2] = (unsigned)f2bf(v0) | ((unsigned)f2bf(v1) << 16);
  }
  __syncthreads();
  int w = tid >> 6, lane = tid & 63;
  int t = w >> 1, ch = w & 1;               // row-tile, column-half
  int m = lane & 15, quad = lane >> 4;
  float4v acc[2] = {{0, 0, 0, 0}, {0, 0, 0, 0}};
#pragma unroll
  for (int ks = 0; ks < 4; ++ks) {
    int koff = quad * 8 + ks * 32;
    short8 af = *(const short8*)&xs[(t * 16 + m) * 136 + koff];
#pragma unroll
    for (int j = 0; j < 2; ++j) {
      int nt = ch * 2 + j;
      short8 bf = *(const short8*)&Wt[(nt * 16 + m) * 136 + koff];
      acc[j] = __builtin_amdgcn_mfma_f32_16x16x32_bf16(af, bf, acc[j], 0, 0, 0);
    }
  }
#pragma unroll
  for (int j = 0; j < 2; ++j) {
    int nt = ch * 2 + j;
#pragma unroll
    for (int reg = 0; reg < 4; ++reg) {
      float v = acc[j][reg];
      float vhi = __shfl_xor(v, 1);          // partner column (m^1)
      int row = row0 + t * 16 + quad * 4 + reg;
      if (!(m & 1) && row < NN) {
        h2u[row * 32 + nt * 8 + (m >> 1)] =
            (unsigned)f2bf(v) | ((unsigned)f2bf(vhi) << 16);
      }
    }
  }
}

// ---------------- K2: weighted aggregate (R12 structure + divergent halves) ----------
// one wave per dst node; each half-wave chases 4 of the node's 8 chains. The while
// condition is HALF-uniform (no __any): when one half's chains all die its lanes
// are exec-masked off and stop issuing loads; halves reconverge at the shfl merge.
__global__ __launch_bounds__(256) void k_agg(
    const unsigned* __restrict__ h2u, const float2* __restrict__ a_src2,
    const float2* __restrict__ a_dst2, const int4* __restrict__ head8v,
    const int4* __restrict__ edge4, const float* __restrict__ bias,
    float* __restrict__ out) {
  int n = blockIdx.x * 4 + (threadIdx.x >> 6);
  int lane = threadIdx.x & 63;
  int c2 = lane & 31;          // column pair: cols 2*c2, 2*c2+1
  int half = lane >> 5;
  int hh = c2 >> 4;

  float denom = 0.f, acc0 = 0.f, acc1 = 0.f;
  if (half == 0) {             // self loop (PyG add_self_loops), counted once
    float2 as = a_src2[n], ad = a_dst2[n];
    float l0 = (hh ? as.y + ad.y : as.x + ad.x);
    l0 = fmaxf(l0, 0.2f * l0);
    float es = __expf(l0);
    unsigned hv = h2u[n * 32 + c2];
    denom = es; acc0 = es * bflo(hv); acc1 = es * bfhi(hv);
  }

  int4 hd = head8v[n * 2 + half];    // 4 chain heads in one 16 B load
  int e0 = hd.x, e1 = hd.y, e2 = hd.z, e3 = hd.w;
  while (max(max(e0, e1), max(e2, e3)) >= 0) {   // half-uniform: halves diverge
    int4 p0 = edge4[max(e0, 0)];
    int4 p1 = edge4[max(e1, 0)];
    int4 p2 = edge4[max(e2, 0)];
    int4 p3 = edge4[max(e3, 0)];
    unsigned h0 = h2u[p0.x * 32 + c2], h1 = h2u[p1.x * 32 + c2];
    unsigned h2 = h2u[p2.x * 32 + c2], h3 = h2u[p3.x * 32 + c2];
    float x0 = (e0 >= 0) ? __int_as_float(hh ? p0.w : p0.z) : 0.f;
    float x1 = (e1 >= 0) ? __int_as_float(hh ? p1.w : p1.z) : 0.f;
    float x2 = (e2 >= 0) ? __int_as_float(hh ? p2.w : p2.z) : 0.f;
    float x3 = (e3 >= 0) ? __int_as_float(hh ? p3.w : p3.z) : 0.f;
    denom += (x0 + x1) + (x2 + x3);
    acc0 += x0 * bflo(h0) + x1 * bflo(h1) + x2 * bflo(h2) + x3 * bflo(h3);
    acc1 += x0 * bfhi(h0) + x1 * bfhi(h1) + x2 * bfhi(h2) + x3 * bfhi(h3);
    e0 = (e0 >= 0) ? p0.y : -1;
    e1 = (e1 >= 0) ? p1.y : -1;
    e2 = (e2 >= 0) ? p2.y : -1;
    e3 = (e3 >= 0) ? p3.y : -1;
  }
  denom += __shfl_xor(denom, 32);    // halves reconverge here
  acc0  += __shfl_xor(acc0, 32);
  acc1  += __shfl_xor(acc1, 32);
  if (half == 0) {
    float inv = 1.f / (denom + 1e-16f);
    float2 b = ((const float2*)bias)[c2];
    ((float2*)out)[n * 32 + c2] = make_float2(acc0 * inv + b.x, acc1 * inv + b.y);
  }
}

extern "C" void kernel_launch(void* const* d_in, const int* in_sizes, int n_in,
                              void* d_out, int out_size, void* d_ws, size_t ws_size,
                              hipStream_t stream) {
  const float* x       = (const float*)d_in[0];
  const float* W       = (const float*)d_in[1];
  const float* att_src = (const float*)d_in[2];
  const float* att_dst = (const float*)d_in[3];
  const float* bias    = (const float*)d_in[4];
  const int* edge_index = (const int*)d_in[5];
  const int* esrc = edge_index;        // edge_index[0, :]
  const int* edst = edge_index + EE;   // edge_index[1, :]

  // Workspace layout:
  char* base = (char*)d_ws;
  unsigned* h2u  = (unsigned*)base;                      // [0     .. 6.4M)   h bf16x2
  float2* a_src2 = (float2*)(base + 6400000);            // [6.4M  .. 6.8M)  50K float2
  float2* a_dst2 = (float2*)(base + 6800000);            // [6.8M  .. 7.2M)  50K float2
  int*    head8  = (int*)(base + 7200000);               // [7.2M  .. 8.8M)  400K i32
  int4*   edge4  = (int4*)(base + 8800000);              // [8.8M  .. 34.4M) 1.6M int4

  const int PRE_BLOCKS = 1024;
  k_pre<<<PRE_BLOCKS, 256, 0, stream>>>(x, W, att_src, att_dst, a_src2, a_dst2,
                                        head8, PRE_BLOCKS);
  k_mid<<<PROJ_BLOCKS + EE / 256, 256, 0, stream>>>(x, W, esrc, edst, a_src2,
                                                    a_dst2, head8, edge4, h2u);
  k_agg<<<NN / 4, 256, 0, stream>>>(h2u, a_src2, a_dst2, (const int4*)head8,
                                    edge4, bias, (float*)d_out);
}